// Round 13
// baseline (364.723 us; speedup 1.0000x reference)
//
#include <hip/hip_runtime.h>
#include <hip/hip_bf16.h>

// InfiniteNeuralNetwork: the scan state stays row-constant, so
//   p[j] = (1/D) * prod_{d,k} cos^2(inf_w[d,j,k])
// and each infinite layer is just tanh(x @ cls_w + cls_b + p).
// Network = 6 GEMMs [2048x2048x2048] with fused epilogues.
// R3: XOR-swizzle fixed 16-way LDS conflicts (93 -> ~41us/GEMM).
// R5: BN=64/BK=32, 512 blocks = 2/CU. 247us.
// R6: LDS-repacked 16B-store epilogue + setprio(1). 219us.
// R7/R9: one barrier per K-step - neutral. R12: depth-5 - neutral.
// R10: B->reg streaming FAILED (4x overfetch). R11: cooperative FAILED.
// => ~28us/GEMM across 5 variants = ~80% LDS-port saturation. Lever is
//    LDS bytes/FLOP (wave-tile area), not scheduling.
// R13: 1-wave 64-thread blocks, tile 64x128 (0.023 B/FLOP ds_read, 2x less),
//      BARRIER-FREE self-paced pipeline (counted vmcnt only, 12 loads/tile,
//      steady vmcnt(24), 4 bufs, 48KB). 512 blocks = 2 waves/CU.

#define DD 2048
#define DEPTH 9

#define BM 64
#define BN 128
#define BK 32
#define NT (DD / BK)     // 64 K-tiles
#define ABUF (BM * BK)   // 2048 shorts = 4KB
#define BBUF (BN * BK)   // 4096 shorts = 8KB
#define NBUF 4

typedef __attribute__((ext_vector_type(8))) short short8;
typedef __attribute__((ext_vector_type(4))) float f32x4;

__device__ __forceinline__ unsigned short f2bf(float f) {
  unsigned u = __float_as_uint(f);
  u += 0x7FFFu + ((u >> 16) & 1u);   // round-to-nearest-even
  return (unsigned short)(u >> 16);
}

// ---------------- fused prep kernel (R12-verified) ----------------
__global__ __launch_bounds__(256) void prep_kernel(
    const float* __restrict__ w0, const float* __restrict__ w1,
    unsigned short* __restrict__ wts, const float* __restrict__ x,
    unsigned short* __restrict__ xb, const float* __restrict__ infw1,
    const float* __restrict__ infw2, const float* __restrict__ clsb1,
    const float* __restrict__ clsb2, float* __restrict__ padd1,
    float* __restrict__ padd2) {
  int b = blockIdx.x;
  int tid = threadIdx.x;
  if (b < 8192) {
    __shared__ float tile[32][33];
    int z = b >> 12;              // 0: w0, 1: w1
    int t = b & 4095;
    const float* src = z ? w1 : w0;
    unsigned short* dst = wts + (size_t)z * DD * DD;
    int bx = (t & 63) * 32;       // n base
    int by = (t >> 6) * 32;       // k base
    int tx = tid & 31, ty = tid >> 5;
#pragma unroll
    for (int i = ty; i < 32; i += 8)
      tile[i][tx] = src[(size_t)(by + i) * DD + bx + tx];
    __syncthreads();
#pragma unroll
    for (int i = ty; i < 32; i += 8)
      dst[(size_t)(bx + i) * DD + by + tx] = f2bf(tile[tx][i]);
  } else if (b < 12288) {
    int i = (b - 8192) * 256 + tid;       // 1,048,576 float4 chunks
    float4 v = reinterpret_cast<const float4*>(x)[i];
    ushort4 o;
    o.x = f2bf(v.x); o.y = f2bf(v.y); o.z = f2bf(v.z); o.w = f2bf(v.w);
    reinterpret_cast<ushort4*>(xb)[i] = o;
  } else {
    int jj = (b - 12288) * 256 + tid;     // 0..4095
    int layer = jj >> 11;
    int j = jj & 2047;
    const float* inf_w = layer ? infw2 : infw1;
    const float* cls_b = layer ? clsb2 : clsb1;
    float* padd = layer ? padd2 : padd1;
    float prod = 1.0f;
#pragma unroll
    for (int d = 0; d < DEPTH; ++d) {
      const float* row = inf_w + ((size_t)d * DD + j) * DD;
      prod *= cosf(row[0]) * cosf(row[1]) * cosf(row[2]);
    }
    padd[j] = cls_b[j] + prod * prod * (1.0f / (float)DD);
  }
}

// ---------------- GEMM (1-wave, barrier-free) ----------------

__device__ __forceinline__ void gload_lds16(const unsigned short* g,
                                            unsigned short* l) {
  __builtin_amdgcn_global_load_lds(
      (const __attribute__((address_space(1))) void*)g,
      (__attribute__((address_space(3))) void*)l, 16, 0, 0);
}

// EPI: 0 = relu -> bf16, 1 = tanh -> bf16, 2 = relu -> f32
// A: [M][K] bf16 row-major. Bt: [N][K] bf16 (transposed weight). bias: [N].
// tsrc/tdst: optional weight transpose tail (for a LATER gemm's weight).
template <int EPI>
__global__ __launch_bounds__(64, 2) void gemm_kernel(
    const unsigned short* __restrict__ A, const unsigned short* __restrict__ Bt,
    const float* __restrict__ bias, unsigned short* __restrict__ Cb,
    float* __restrict__ Cf, const float* __restrict__ tsrc,
    unsigned short* __restrict__ tdst) {
  const int K = DD;
  // 48KB union: 4 x (4KB A + 8KB B) pipeline bufs / epilogue f32 tile
  // (64*132*4 = 33792B) / tail transpose tile (64*65*4 = 16.6KB).
  __shared__ __align__(16) unsigned char smem[49152];
  unsigned short* As = (unsigned short*)smem;                    // 4 x 2048 el
  unsigned short* Bs = (unsigned short*)(smem + NBUF * ABUF * 2);// 4 x 4096 el

  int lane = threadIdx.x;          // single wave
  int lr = lane & 15;
  int lg = lane >> 4;

  // XCD-aware bijective swizzle over 512 blocks (512 % 8 == 0).
  int bid = blockIdx.x;
  int swz = (bid & 7) * 64 + (bid >> 3);
  int bcol = (swz & 15) * BN;   // 16 n-tiles
  int brow = (swz >> 4) * BM;   // 32 m-tiles

  const unsigned short* Abase = A + (size_t)brow * K;
  const unsigned short* Bbase = Bt + (size_t)bcol * K;

  // Staging (rule 21): LDS dest linear (wave-uniform base + lane*16B);
  // SOURCE slot pre-swizzled with the reader's involution
  // slot' = slot ^ ((row>>1)&3). 12 gload_lds/lane/tile -> vmcnt units.
  auto stage = [&](int buf, int tile) {
    int kt = tile * BK;
#pragma unroll
    for (int r = 0; r < 4; ++r) {          // A: 64 rows x 4 slots = 256 chunks
      int c = r * 64 + lane;
      int row = c >> 2, sp = c & 3;
      int kof = (sp ^ ((row >> 1) & 3)) * 8;
      gload_lds16(Abase + (size_t)row * K + kt + kof,
                  As + buf * ABUF + r * 512);
    }
#pragma unroll
    for (int r = 0; r < 8; ++r) {          // B: 128 rows x 4 slots = 512 chunks
      int c = r * 64 + lane;
      int row = c >> 2, sp = c & 3;
      int kof = (sp ^ ((row >> 1) & 3)) * 8;
      gload_lds16(Bbase + (size_t)row * K + kt + kof,
                  Bs + buf * BBUF + r * 512);
    }
  };

  f32x4 acc[4][8];
#pragma unroll
  for (int i = 0; i < 4; ++i)
#pragma unroll
    for (int j = 0; j < 8; ++j) acc[i][j] = f32x4{0.f, 0.f, 0.f, 0.f};

  auto compute = [&](int buf) {
    short8 a[4], b[8];
#pragma unroll
    for (int mt = 0; mt < 4; ++mt) {
      int row = mt * 16 + lr;
      int slot = lg ^ ((row >> 1) & 3);
      a[mt] = *reinterpret_cast<const short8*>(
          &As[buf * ABUF + row * BK + slot * 8]);
    }
#pragma unroll
    for (int nt = 0; nt < 8; ++nt) {
      int row = nt * 16 + lr;
      int slot = lg ^ ((row >> 1) & 3);
      b[nt] = *reinterpret_cast<const short8*>(
          &Bs[buf * BBUF + row * BK + slot * 8]);
    }
    __builtin_amdgcn_s_setprio(1);
#pragma unroll
    for (int mt = 0; mt < 4; ++mt)
#pragma unroll
      for (int nt = 0; nt < 8; ++nt)
        acc[mt][nt] = __builtin_amdgcn_mfma_f32_16x16x32_bf16(
            a[mt], b[nt], acc[mt][nt], 0, 0, 0);
    __builtin_amdgcn_s_setprio(0);
  };

  // Barrier-free step: single wave self-paces on vmcnt only.
  // wcase: 0 -> vmcnt(24) (2 newer tiles in flight), 1 -> 12, 2 -> 0.
  // stage(t+3) targets buf (t-1)&3, whose ds_reads completed before step
  // t-1's MFMAs consumed them (in-order wave) -> write-after-read safe.
  auto step = [&](int buf, int pf, int wc) {
    if (wc == 0) asm volatile("s_waitcnt vmcnt(24)" ::: "memory");
    else if (wc == 1) asm volatile("s_waitcnt vmcnt(12)" ::: "memory");
    else asm volatile("s_waitcnt vmcnt(0)" ::: "memory");
    __builtin_amdgcn_sched_barrier(0);
    if (pf < NT) stage(pf & 3, pf);        // issue loads before ds_reads
    compute(buf);
  };

  stage(0, 0); stage(1, 1); stage(2, 2);   // 36 loads in flight
#pragma unroll 1
  for (int i = 0; i < 15; ++i) {           // steps 0..59
    int t = 4 * i;
    step(0, t + 3, 0);
    step(1, t + 4, 0);
    step(2, t + 5, 0);
    step(3, t + 6, 0);
  }
  step(0, 63, 0);                          // step 60: stage tile 63
  step(1, NT, 0);                          // step 61 (62,63 in flight = 24)
  step(2, NT, 1);                          // step 62: vmcnt(12)
  step(3, NT, 2);                          // step 63: vmcnt(0)

  // ---- epilogue: LDS-repack to coalesced 16B stores (no barrier: 1 wave).
  // C/D layout col=lane&15, row=(lane>>4)*4+reg [m89-verified].
  {
    float* et = reinterpret_cast<float*>(smem);   // [64][132] f32
    asm volatile("s_waitcnt lgkmcnt(0)" ::: "memory");
    __builtin_amdgcn_sched_barrier(0);
#pragma unroll
    for (int nt = 0; nt < 8; ++nt) {
      int colb = nt * 16 + lr;
      float bs = bias[bcol + colb];
#pragma unroll
      for (int mt = 0; mt < 4; ++mt) {
#pragma unroll
        for (int i = 0; i < 4; ++i) {
          int rowb = mt * 16 + lg * 4 + i;
          float v = acc[mt][nt][i] + bs;
          v = (EPI == 1) ? tanhf(v) : fmaxf(v, 0.0f);
          et[rowb * 132 + colb] = v;
        }
      }
    }
    asm volatile("s_waitcnt lgkmcnt(0)" ::: "memory");
    __builtin_amdgcn_sched_barrier(0);
#pragma unroll
    for (int it = 0; it < 16; ++it) {
      int c = it * 64 + lane;              // 1024 chunks of 8 f32
      int rowb = c >> 4;
      int c8 = (c & 15) * 8;
      float4 v0 = *reinterpret_cast<const float4*>(&et[rowb * 132 + c8]);
      float4 v1 = *reinterpret_cast<const float4*>(&et[rowb * 132 + c8 + 4]);
      size_t g = (size_t)(brow + rowb) * DD + bcol + c8;
      if (EPI == 2) {
        *reinterpret_cast<float4*>(&Cf[g]) = v0;
        *reinterpret_cast<float4*>(&Cf[g + 4]) = v1;
      } else {
        uint4 o;
        o.x = (unsigned)f2bf(v0.x) | ((unsigned)f2bf(v0.y) << 16);
        o.y = (unsigned)f2bf(v0.z) | ((unsigned)f2bf(v0.w) << 16);
        o.z = (unsigned)f2bf(v1.x) | ((unsigned)f2bf(v1.y) << 16);
        o.w = (unsigned)f2bf(v1.z) | ((unsigned)f2bf(v1.w) << 16);
        *reinterpret_cast<uint4*>(&Cb[g]) = o;
      }
    }
  }

  // ---- transpose tail: tdst[n*D+k] = bf16(tsrc[k*D+n]) for a later GEMM.
  // 1024 64x64 tiles over 512 blocks = 2 tiles/block. No barriers (1 wave).
  if (tsrc != nullptr) {
    float* ft = reinterpret_cast<float*>(smem);  // 64*65 f32 = 16.6KB
#pragma unroll 1
    for (int t2 = 0; t2 < 2; ++t2) {
      int tau = bid * 2 + t2;
      int bx = (tau & 31) * 64;   // n base
      int by = (tau >> 5) * 64;   // k base
      asm volatile("s_waitcnt lgkmcnt(0)" ::: "memory");   // prev reads done
      __builtin_amdgcn_sched_barrier(0);
#pragma unroll
      for (int it = 0; it < 16; ++it) {
        int idx = it * 64 + lane;
        int r = idx >> 4, c4 = (idx & 15) * 4;
        float4 v = *reinterpret_cast<const float4*>(
            &tsrc[(size_t)(by + r) * DD + bx + c4]);
        ft[r * 65 + c4 + 0] = v.x;
        ft[r * 65 + c4 + 1] = v.y;
        ft[r * 65 + c4 + 2] = v.z;
        ft[r * 65 + c4 + 3] = v.w;
      }
      asm volatile("s_waitcnt lgkmcnt(0)" ::: "memory");
      __builtin_amdgcn_sched_barrier(0);
#pragma unroll
      for (int it = 0; it < 16; ++it) {
        int idx = it * 64 + lane;
        int n = idx >> 4, kq = idx & 15;
        ushort4 o;
        o.x = f2bf(ft[(kq * 4 + 0) * 65 + n]);
        o.y = f2bf(ft[(kq * 4 + 1) * 65 + n]);
        o.z = f2bf(ft[(kq * 4 + 2) * 65 + n]);
        o.w = f2bf(ft[(kq * 4 + 3) * 65 + n]);
        *reinterpret_cast<ushort4*>(&tdst[(size_t)(bx + n) * DD + by + kq * 4]) = o;
      }
    }
  }
}

// ---------------- launch ----------------

extern "C" void kernel_launch(void* const* d_in, const int* in_sizes, int n_in,
                              void* d_out, int out_size, void* d_ws,
                              size_t ws_size, hipStream_t stream) {
  const float* x     = (const float*)d_in[0];
  const float* w0    = (const float*)d_in[1];
  const float* b0    = (const float*)d_in[2];
  const float* w1    = (const float*)d_in[3];
  const float* b1    = (const float*)d_in[4];
  const float* infw1 = (const float*)d_in[5];
  const float* clsw1 = (const float*)d_in[6];
  const float* clsb1 = (const float*)d_in[7];
  const float* w2    = (const float*)d_in[8];
  const float* b2    = (const float*)d_in[9];
  const float* infw2 = (const float*)d_in[10];
  const float* clsw2 = (const float*)d_in[11];
  const float* clsb2 = (const float*)d_in[12];
  const float* w3    = (const float*)d_in[13];
  const float* b3    = (const float*)d_in[14];
  float* out = (float*)d_out;

  char* ws = (char*)d_ws;
  const size_t MB = 1ull << 20;
  const size_t DDe = (size_t)DD * DD;
  unsigned short* buf0 = (unsigned short*)ws;              // 8 MB (x_bf16 / act)
  unsigned short* buf1 = (unsigned short*)(ws + 8 * MB);   // 8 MB (act)
  unsigned short* wts  = (unsigned short*)(ws + 16 * MB);  // 6 x 8 MB
  float* padd1 = (float*)(ws + 64 * MB);
  float* padd2 = padd1 + DD;

  prep_kernel<<<12304, 256, 0, stream>>>(w0, w1, wts, x, buf0, infw1, infw2,
                                         clsb1, clsb2, padd1, padd2);

  dim3 gg((DD / BM) * (DD / BN));  // 512 blocks x 64 threads -> 2 waves/CU
  // GEMM_i tail-transposes the weight consumed by GEMM_{i+2} (stream order
  // guarantees GEMM_i completes before GEMM_{i+1} starts).
  gemm_kernel<0><<<gg, 64, 0, stream>>>(buf0, wts + 0 * DDe, b0,    buf1,
                                        nullptr, clsw1, wts + 2 * DDe);
  gemm_kernel<0><<<gg, 64, 0, stream>>>(buf1, wts + 1 * DDe, b1,    buf0,
                                        nullptr, w2,    wts + 3 * DDe);
  gemm_kernel<1><<<gg, 64, 0, stream>>>(buf0, wts + 2 * DDe, padd1, buf1,
                                        nullptr, clsw2, wts + 4 * DDe);
  gemm_kernel<0><<<gg, 64, 0, stream>>>(buf1, wts + 3 * DDe, b2,    buf0,
                                        nullptr, w3,    wts + 5 * DDe);
  gemm_kernel<1><<<gg, 64, 0, stream>>>(buf0, wts + 4 * DDe, padd2, buf1,
                                        nullptr, nullptr, nullptr);
  gemm_kernel<2><<<gg, 64, 0, stream>>>(buf1, wts + 5 * DDe, b3,    nullptr,
                                        out, nullptr, nullptr);
}

// Round 14
// 184.559 us; speedup vs baseline: 1.9762x; 1.9762x over previous
//
#include <hip/hip_runtime.h>
#include <hip/hip_bf16.h>

// InfiniteNeuralNetwork: the scan state stays row-constant, so
//   p[j] = (1/D) * prod_{d,k} cos^2(inf_w[d,j,k])
// and each infinite layer is just tanh(x @ cls_w + cls_b + p).
// Network = 6 GEMMs [2048x2048x2048] with fused epilogues.
// R3: XOR-swizzle fixed 16-way LDS conflicts (93 -> ~41us/GEMM).
// R5: BN=64/BK=32, 512 blocks = 2/CU. 247us.
// R6: LDS-repacked 16B-store epilogue + setprio(1). 219us. (best)
// R7/R9: 1 barrier/step - neutral. R12: depth-5 - neutral.
// R10: B->reg streaming FAILED (4x overfetch). R11: cooperative FAILED.
// R13: 1-wave blocks FAILED (0.5 waves/SIMD, latency-bound, 143us/GEMM).
// Model: LDS port ~80% saturated (floor ~22us) + rendezvous overhead.
// R14: BK=64 at 2 blocks/CU (untested cell): halves step count ->
//      halves barrier/wait rendezvous; traffic & occupancy unchanged.
//      Swizzle -> 8 slots/row: slot' = slot ^ ((row>>1)&7).

#define DD 2048
#define DEPTH 9

#define BM 128
#define BN 64
#define BK 64
#define NT (DD / BK)     // 32 K-tiles
#define ABUF (BM * BK)   // 8192 shorts = 16KB
#define BBUF (BN * BK)   // 4096 shorts = 8KB

typedef __attribute__((ext_vector_type(8))) short short8;
typedef __attribute__((ext_vector_type(4))) float f32x4;

__device__ __forceinline__ unsigned short f2bf(float f) {
  unsigned u = __float_as_uint(f);
  u += 0x7FFFu + ((u >> 16) & 1u);   // round-to-nearest-even
  return (unsigned short)(u >> 16);
}

// ---------------- fused prep kernel (R12-verified) ----------------
__global__ __launch_bounds__(256) void prep_kernel(
    const float* __restrict__ w0, const float* __restrict__ w1,
    unsigned short* __restrict__ wts, const float* __restrict__ x,
    unsigned short* __restrict__ xb, const float* __restrict__ infw1,
    const float* __restrict__ infw2, const float* __restrict__ clsb1,
    const float* __restrict__ clsb2, float* __restrict__ padd1,
    float* __restrict__ padd2) {
  int b = blockIdx.x;
  int tid = threadIdx.x;
  if (b < 8192) {
    __shared__ float tile[32][33];
    int z = b >> 12;              // 0: w0, 1: w1
    int t = b & 4095;
    const float* src = z ? w1 : w0;
    unsigned short* dst = wts + (size_t)z * DD * DD;
    int bx = (t & 63) * 32;       // n base
    int by = (t >> 6) * 32;       // k base
    int tx = tid & 31, ty = tid >> 5;
#pragma unroll
    for (int i = ty; i < 32; i += 8)
      tile[i][tx] = src[(size_t)(by + i) * DD + bx + tx];
    __syncthreads();
#pragma unroll
    for (int i = ty; i < 32; i += 8)
      dst[(size_t)(bx + i) * DD + by + tx] = f2bf(tile[tx][i]);
  } else if (b < 12288) {
    int i = (b - 8192) * 256 + tid;       // 1,048,576 float4 chunks
    float4 v = reinterpret_cast<const float4*>(x)[i];
    ushort4 o;
    o.x = f2bf(v.x); o.y = f2bf(v.y); o.z = f2bf(v.z); o.w = f2bf(v.w);
    reinterpret_cast<ushort4*>(xb)[i] = o;
  } else {
    int jj = (b - 12288) * 256 + tid;     // 0..4095
    int layer = jj >> 11;
    int j = jj & 2047;
    const float* inf_w = layer ? infw2 : infw1;
    const float* cls_b = layer ? clsb2 : clsb1;
    float* padd = layer ? padd2 : padd1;
    float prod = 1.0f;
#pragma unroll
    for (int d = 0; d < DEPTH; ++d) {
      const float* row = inf_w + ((size_t)d * DD + j) * DD;
      prod *= cosf(row[0]) * cosf(row[1]) * cosf(row[2]);
    }
    padd[j] = cls_b[j] + prod * prod * (1.0f / (float)DD);
  }
}

// ---------------- GEMM ----------------

__device__ __forceinline__ void gload_lds16(const unsigned short* g,
                                            unsigned short* l) {
  __builtin_amdgcn_global_load_lds(
      (const __attribute__((address_space(1))) void*)g,
      (__attribute__((address_space(3))) void*)l, 16, 0, 0);
}

// EPI: 0 = relu -> bf16, 1 = tanh -> bf16, 2 = relu -> f32
// A: [M][K] bf16 row-major. Bt: [N][K] bf16 (transposed weight). bias: [N].
// tsrc/tdst: optional weight transpose tail (for a LATER gemm's weight).
template <int EPI>
__global__ __launch_bounds__(256) void gemm_kernel(
    const unsigned short* __restrict__ A, const unsigned short* __restrict__ Bt,
    const float* __restrict__ bias, unsigned short* __restrict__ Cb,
    float* __restrict__ Cf, const float* __restrict__ tsrc,
    unsigned short* __restrict__ tdst) {
  const int N = DD, K = DD;
  // 72KB union: 3 pipeline buffer pairs (3 x (16KB A + 8KB B)) /
  // epilogue f32 tile (128*68*4 = 34816B) / tail transpose (64*65*4).
  __shared__ __align__(16) unsigned char smem[73728];
  unsigned short* As = (unsigned short*)smem;                 // 3 x 8192 el
  unsigned short* Bs = (unsigned short*)(smem + 3 * ABUF * 2);// 3 x 4096 el

  int tid = threadIdx.x;
  int wid = tid >> 6, lane = tid & 63;
  int wr = wid >> 1, wc = wid & 1;   // wave grid 2x2, wave tile 64x32
  int lr = lane & 15;
  int lg = lane >> 4;

  // XCD-aware bijective swizzle over 512 blocks (512 % 8 == 0).
  int bid = blockIdx.x;
  int swz = (bid & 7) * 64 + (bid >> 3);
  int bcol = (swz & 31) * BN;   // 32 n-tiles
  int brow = (swz >> 5) * BM;   // 16 m-tiles

  const unsigned short* Abase = A + (size_t)brow * K;
  const unsigned short* Bbase = Bt + (size_t)bcol * K;

  // Staging (rule 21): LDS dest linear; SOURCE slot pre-swizzled with the
  // same involution the reader applies: slot' = slot ^ ((row>>1)&7).
  // 8 x 16B slots per 128B row. 6 gload_lds per thread per tile (4 A + 2 B).
  auto stage = [&](int buf, int tile) {
    int kt = tile * BK;
#pragma unroll
    for (int r = 0; r < 4; ++r) {
      int chunk = r * 256 + tid;          // A: 128 rows x 8 slots = 1024
      int row = chunk >> 3;
      int sp = chunk & 7;
      int kof = (sp ^ ((row >> 1) & 7)) * 8;
      gload_lds16(Abase + (size_t)row * K + kt + kof,
                  As + buf * ABUF + (size_t)(r * 256 + wid * 64) * 8);
    }
#pragma unroll
    for (int r = 0; r < 2; ++r) {
      int chunk = r * 256 + tid;          // B: 64 rows x 8 slots = 512
      int row = chunk >> 3;
      int sp = chunk & 7;
      int kof = (sp ^ ((row >> 1) & 7)) * 8;
      gload_lds16(Bbase + (size_t)row * K + kt + kof,
                  Bs + buf * BBUF + (size_t)(r * 256 + wid * 64) * 8);
    }
  };

  f32x4 acc[4][2];
#pragma unroll
  for (int i = 0; i < 4; ++i)
#pragma unroll
    for (int j = 0; j < 2; ++j) acc[i][j] = f32x4{0.f, 0.f, 0.f, 0.f};

  auto compute = [&](int buf) {
#pragma unroll
    for (int ks = 0; ks < 2; ++ks) {
      short8 a[4], b[2];
#pragma unroll
      for (int mt = 0; mt < 4; ++mt) {
        int row = wr * 64 + mt * 16 + lr;
        int slot = (ks * 4 + lg) ^ ((row >> 1) & 7);
        a[mt] = *reinterpret_cast<const short8*>(
            &As[buf * ABUF + row * BK + slot * 8]);
      }
#pragma unroll
      for (int nt = 0; nt < 2; ++nt) {
        int row = wc * 32 + nt * 16 + lr;
        int slot = (ks * 4 + lg) ^ ((row >> 1) & 7);
        b[nt] = *reinterpret_cast<const short8*>(
            &Bs[buf * BBUF + row * BK + slot * 8]);
      }
      __builtin_amdgcn_s_setprio(1);       // T5
#pragma unroll
      for (int mt = 0; mt < 4; ++mt)
#pragma unroll
        for (int nt = 0; nt < 2; ++nt)
          acc[mt][nt] = __builtin_amdgcn_mfma_f32_16x16x32_bf16(
              a[mt], b[nt], acc[mt][nt], 0, 0, 0);
      __builtin_amdgcn_s_setprio(0);
    }
  };

  // R6-verified two-barrier step, 3 buffers, tile t in buf t%3.
  // 6 loads/thread/tile; steady vmcnt(12) = 2 newer tiles in flight.
  // wcase: 0 -> vmcnt(12), 1 -> vmcnt(6), 2 -> vmcnt(0).
  auto step = [&](int buf, int pf_tile, int wcase) {
    if (wcase == 0) asm volatile("s_waitcnt vmcnt(12)" ::: "memory");
    else if (wcase == 1) asm volatile("s_waitcnt vmcnt(6)" ::: "memory");
    else asm volatile("s_waitcnt vmcnt(0)" ::: "memory");
    __builtin_amdgcn_s_barrier();          // buffer `buf` fully written
    __builtin_amdgcn_sched_barrier(0);
    compute(buf);
    asm volatile("s_waitcnt lgkmcnt(0)" ::: "memory");  // my ds_reads done
    __builtin_amdgcn_s_barrier();          // all waves done reading `buf`
    __builtin_amdgcn_sched_barrier(0);
    if (pf_tile < NT) stage(pf_tile % 3, pf_tile);
  };

  stage(0, 0); stage(1, 1); stage(2, 2);   // 18 loads/thread in flight
#pragma unroll 1
  for (int i = 0; i < 10; ++i) {           // steps 0..29
    int t = 3 * i;
    step(0, t + 3, 0);
    step(1, t + 4, 0);
    step(2, t + 5, 0);
  }
  step(0, NT, 1);                          // step 30: vmcnt(6)
  step(1, NT, 2);                          // step 31: vmcnt(0)

  // ---- epilogue: LDS-repack to coalesced 16B stores.
  // C/D layout col=lane&15, row=(lane>>4)*4+reg [m89-verified].
  {
    float* et = reinterpret_cast<float*>(smem);   // [128][68] f32
    __syncthreads();                              // pipeline LDS dead now
#pragma unroll
    for (int nt = 0; nt < 2; ++nt) {
      int colb = wc * 32 + nt * 16 + lr;
      float bs = bias[bcol + colb];
#pragma unroll
      for (int mt = 0; mt < 4; ++mt) {
#pragma unroll
        for (int i = 0; i < 4; ++i) {
          int rowb = wr * 64 + mt * 16 + lg * 4 + i;
          float v = acc[mt][nt][i] + bs;
          v = (EPI == 1) ? tanhf(v) : fmaxf(v, 0.0f);
          et[rowb * 68 + colb] = v;
        }
      }
    }
    __syncthreads();
#pragma unroll
    for (int it = 0; it < 4; ++it) {
      int chunk = it * 256 + tid;          // 1024 chunks of 8 elements
      int rowb = chunk >> 3;
      int c8 = (chunk & 7) * 8;
      float4 v0 = *reinterpret_cast<const float4*>(&et[rowb * 68 + c8]);
      float4 v1 = *reinterpret_cast<const float4*>(&et[rowb * 68 + c8 + 4]);
      size_t g = (size_t)(brow + rowb) * N + bcol + c8;
      if (EPI == 2) {
        *reinterpret_cast<float4*>(&Cf[g]) = v0;
        *reinterpret_cast<float4*>(&Cf[g + 4]) = v1;
      } else {
        uint4 o;
        o.x = (unsigned)f2bf(v0.x) | ((unsigned)f2bf(v0.y) << 16);
        o.y = (unsigned)f2bf(v0.z) | ((unsigned)f2bf(v0.w) << 16);
        o.z = (unsigned)f2bf(v1.x) | ((unsigned)f2bf(v1.y) << 16);
        o.w = (unsigned)f2bf(v1.z) | ((unsigned)f2bf(v1.w) << 16);
        *reinterpret_cast<uint4*>(&Cb[g]) = o;
      }
    }
  }

  // ---- transpose tail: tdst[n*D+k] = bf16(tsrc[k*D+n]) for a later GEMM.
  // 1024 64x64 tiles over 512 blocks = 2 tiles/block.
  if (tsrc != nullptr) {
    float* ft = reinterpret_cast<float*>(smem);  // 64*65 f32 = 16.6KB
    __syncthreads();
#pragma unroll 1
    for (int t2 = 0; t2 < 2; ++t2) {
      int tau = bid * 2 + t2;
      int bx = (tau & 31) * 64;   // n base
      int by = (tau >> 5) * 64;   // k base
      if (t2) __syncthreads();
#pragma unroll
      for (int it = 0; it < 4; ++it) {
        int idx = it * 256 + tid;
        int r = idx >> 4, c4 = (idx & 15) * 4;
        float4 v = *reinterpret_cast<const float4*>(
            &tsrc[(size_t)(by + r) * DD + bx + c4]);
        ft[r * 65 + c4 + 0] = v.x;
        ft[r * 65 + c4 + 1] = v.y;
        ft[r * 65 + c4 + 2] = v.z;
        ft[r * 65 + c4 + 3] = v.w;
      }
      __syncthreads();
#pragma unroll
      for (int it = 0; it < 4; ++it) {
        int idx = it * 256 + tid;
        int n = idx >> 4, kq = idx & 15;
        ushort4 o;
        o.x = f2bf(ft[(kq * 4 + 0) * 65 + n]);
        o.y = f2bf(ft[(kq * 4 + 1) * 65 + n]);
        o.z = f2bf(ft[(kq * 4 + 2) * 65 + n]);
        o.w = f2bf(ft[(kq * 4 + 3) * 65 + n]);
        *reinterpret_cast<ushort4*>(&tdst[(size_t)(bx + n) * DD + by + kq * 4]) = o;
      }
    }
  }
}

// ---------------- launch ----------------

extern "C" void kernel_launch(void* const* d_in, const int* in_sizes, int n_in,
                              void* d_out, int out_size, void* d_ws,
                              size_t ws_size, hipStream_t stream) {
  const float* x     = (const float*)d_in[0];
  const float* w0    = (const float*)d_in[1];
  const float* b0    = (const float*)d_in[2];
  const float* w1    = (const float*)d_in[3];
  const float* b1    = (const float*)d_in[4];
  const float* infw1 = (const float*)d_in[5];
  const float* clsw1 = (const float*)d_in[6];
  const float* clsb1 = (const float*)d_in[7];
  const float* w2    = (const float*)d_in[8];
  const float* b2    = (const float*)d_in[9];
  const float* infw2 = (const float*)d_in[10];
  const float* clsw2 = (const float*)d_in[11];
  const float* clsb2 = (const float*)d_in[12];
  const float* w3    = (const float*)d_in[13];
  const float* b3    = (const float*)d_in[14];
  float* out = (float*)d_out;

  char* ws = (char*)d_ws;
  const size_t MB = 1ull << 20;
  const size_t DDe = (size_t)DD * DD;
  unsigned short* buf0 = (unsigned short*)ws;              // 8 MB (x_bf16 / act)
  unsigned short* buf1 = (unsigned short*)(ws + 8 * MB);   // 8 MB (act)
  unsigned short* wts  = (unsigned short*)(ws + 16 * MB);  // 6 x 8 MB
  float* padd1 = (float*)(ws + 64 * MB);
  float* padd2 = padd1 + DD;

  prep_kernel<<<12304, 256, 0, stream>>>(w0, w1, wts, x, buf0, infw1, infw2,
                                         clsb1, clsb2, padd1, padd2);

  dim3 gg((DD / BM) * (DD / BN));  // 512 blocks -> 2 blocks/CU
  // GEMM_i tail-transposes the weight consumed by GEMM_{i+2} (stream order
  // guarantees GEMM_i completes before GEMM_{i+1} starts).
  gemm_kernel<0><<<gg, 256, 0, stream>>>(buf0, wts + 0 * DDe, b0,    buf1,
                                         nullptr, clsw1, wts + 2 * DDe);
  gemm_kernel<0><<<gg, 256, 0, stream>>>(buf1, wts + 1 * DDe, b1,    buf0,
                                         nullptr, w2,    wts + 3 * DDe);
  gemm_kernel<1><<<gg, 256, 0, stream>>>(buf0, wts + 2 * DDe, padd1, buf1,
                                         nullptr, clsw2, wts + 4 * DDe);
  gemm_kernel<0><<<gg, 256, 0, stream>>>(buf1, wts + 3 * DDe, b2,    buf0,
                                         nullptr, w3,    wts + 5 * DDe);
  gemm_kernel<1><<<gg, 256, 0, stream>>>(buf0, wts + 4 * DDe, padd2, buf1,
                                         nullptr, nullptr, nullptr);
  gemm_kernel<2><<<gg, 256, 0, stream>>>(buf1, wts + 5 * DDe, b3,    nullptr,
                                         out, nullptr, nullptr);
}